// Round 4
// baseline (351.438 us; speedup 1.0000x reference)
//
#include <hip/hip_runtime.h>

// Problem constants (fixed by the reference):
//   B=2, N=50000, F=8, E=800000, D=3, K=8, H=64, FB=F*B=16, FK=F*K=64
#define KC 8
#define FC 8
#define BC 2
#define HC 64
#define KD 24        // K*D
#define EPSF 1e-14f

// ---------------- K0: zero degree counters ----------------
__global__ void k0_zero(int* __restrict__ counts, int N) {
    int i = blockIdx.x * 256 + threadIdx.x;
    if (i < N) counts[i] = 0;
}

// ---------------- K1: row-degree histogram ----------------
__global__ void k1_hist(const int* __restrict__ u_rows, int* __restrict__ counts, int E) {
    int e = blockIdx.x * 256 + threadIdx.x;
    if (e < E) atomicAdd(&counts[u_rows[e]], 1);
}

// ---------------- K2: single-block exclusive scan counts->row_start; zero fill ----------------
__global__ __launch_bounds__(1024) void k2_scan(const int* __restrict__ counts,
                                                int* __restrict__ row_start,
                                                int* __restrict__ fill, int N, int E) {
    __shared__ int s[1024];
    int t = threadIdx.x;
    const int CH = (N + 1023) / 1024;          // 49 for N=50000
    int lo = t * CH;
    int hi = lo + CH; if (hi > N) hi = N; if (lo > N) lo = N;
    int sum = 0;
    for (int i = lo; i < hi; i++) sum += counts[i];
    s[t] = sum;
    __syncthreads();
    for (int off = 1; off < 1024; off <<= 1) {  // inclusive block scan
        int add = (t >= off) ? s[t - off] : 0;
        __syncthreads();
        s[t] += add;
        __syncthreads();
    }
    int run = s[t] - sum;                       // exclusive prefix of this chunk
    for (int i = lo; i < hi; i++) {
        row_start[i] = run;
        fill[i] = 0;
        run += counts[i];
    }
    if (t == 1023) row_start[N] = E;
}

// ---------------- K3: per-edge e-values (m=0 softmax numerator) into CSR slots ----------------
// Softmax is shift-invariant; logits <= 0 so e = exp(logit) in (0,1]. Full-row
// underflow would need every edge of a (row,k) below logit -87 (per-edge
// P ~ 2e-10 for this data) -> impossible; den >= tiny > 0 always in practice.
// Each edge computed ONCE here (vs 16x redundantly per-lane in k4).
__global__ void k3_evals(const float* __restrict__ u_val, const int* __restrict__ u_rows,
                         const int* __restrict__ u_cols, const int* __restrict__ row_start,
                         int* __restrict__ fill, const float* __restrict__ mu,
                         const float* __restrict__ sigma, float* __restrict__ evals,
                         int* __restrict__ cols_s, int E) {
    __shared__ float s_mu[KD], s_inv[KD];
    int t = threadIdx.x;
    if (t < KD) { s_mu[t] = mu[t]; float sg = sigma[t]; s_inv[t] = 1.0f / (sg * sg + EPSF); }
    __syncthreads();
    int e = blockIdx.x * 256 + t;
    if (e >= E) return;
    int r = u_rows[e];
    int pos = row_start[r] + atomicAdd(&fill[r], 1);
    cols_s[pos] = u_cols[e];
    float v0 = u_val[e * 3 + 0], v1 = u_val[e * 3 + 1], v2 = u_val[e * 3 + 2];
    float ev[KC];
#pragma unroll
    for (int k = 0; k < KC; k++) {
        float d0 = v0 - s_mu[k * 3 + 0];
        float d1 = v1 - s_mu[k * 3 + 1];
        float d2 = v2 - s_mu[k * 3 + 2];
        float s = d0 * d0 * s_inv[k * 3 + 0];
        s = fmaf(d1 * d1, s_inv[k * 3 + 1], s);
        s = fmaf(d2 * d2, s_inv[k * 3 + 2], s);
        ev[k] = __expf(-0.5f * s);
    }
    float4* p = (float4*)(evals + (size_t)pos * KC);
    p[0] = make_float4(ev[0], ev[1], ev[2], ev[3]);
    p[1] = make_float4(ev[4], ev[5], ev[6], ev[7]);
}

// ---------------- K4: per-row aggregation + fused 64x64 GEMM ----------------
// One wave per row. lane = kb*16 + fb; fb = f*2 + b (matches X_t col f*B+b).
// Edge loop: evals read is SEQUENTIAL (CSR order, 32B/edge, fully coalesced);
// no LDS use at all (LDS pipe left free for the GEMM phase). Unnormalized
// accumulation + one divide at the end == per-edge normalization exactly.
// GEMM: GW staged in LDS pair-interleaved [f/2][k][h][2] so each lane reads
// float2 (2-way bank alias = free) and feats come as float4 broadcasts.
__global__ __launch_bounds__(256) void k4_row(const float* __restrict__ X,
                                              const float* __restrict__ evals,
                                              const int* __restrict__ cols_s,
                                              const int* __restrict__ row_start,
                                              const float* __restrict__ GW,
                                              float* __restrict__ out, int N) {
    __shared__ float s_gw2[64 * 64];  // 16 KB: [fp=f>>1][k][h][f&1]
    __shared__ float s_feat[4][128];  // per-wave feats [k][fb]
    int t = threadIdx.x;
    // Stage GW swizzled: src i = fk*64 + h; dst = ((fp*8+k)*64 + h)*2 + (f&1).
    for (int i = t; i < 64 * 64; i += 256) {
        int fk = i >> 6, h = i & 63;
        int f = fk >> 3, k = fk & 7;
        int dst = (((f >> 1) * 8 + k) * 64 + h) * 2 + (f & 1);
        s_gw2[dst] = GW[i];
    }

    int wv = t >> 6, lane = t & 63;
    int n = blockIdx.x * 4 + wv;
    int kb = lane >> 4, fb = lane & 15;
    int b = fb & 1, f = fb >> 1;

    bool valid = (n < N);
    int start = valid ? row_start[n] : 0;
    int end   = valid ? row_start[n + 1] : 0;

    const float* Xb = X + (size_t)b * (size_t)N * FC + f;   // X[b, c, f] at Xb[c*8]

    float acc0 = 0.0f, acc1 = 0.0f, den0 = 0.0f, den1 = 0.0f;
    float acc0b = 0.0f, acc1b = 0.0f, den0b = 0.0f, den1b = 0.0f;
    int i = start;
    for (; i + 1 < end; i += 2) {      // 2x unroll, independent accumulators for ILP
        float e00 = evals[(size_t)i * KC + kb];
        float e01 = evals[(size_t)i * KC + kb + 4];
        float e10 = evals[(size_t)(i + 1) * KC + kb];
        float e11 = evals[(size_t)(i + 1) * KC + kb + 4];
        int c0 = cols_s[i];
        int c1 = cols_s[i + 1];
        float x0 = Xb[(size_t)c0 * FC];
        float x1 = Xb[(size_t)c1 * FC];
        den0  += e00; den1  += e01;
        den0b += e10; den1b += e11;
        acc0  = fmaf(e00, x0, acc0);
        acc1  = fmaf(e01, x0, acc1);
        acc0b = fmaf(e10, x1, acc0b);
        acc1b = fmaf(e11, x1, acc1b);
    }
    if (i < end) {
        float e00 = evals[(size_t)i * KC + kb];
        float e01 = evals[(size_t)i * KC + kb + 4];
        int c0 = cols_s[i];
        float x0 = Xb[(size_t)c0 * FC];
        den0 += e00; den1 += e01;
        acc0 = fmaf(e00, x0, acc0);
        acc1 = fmaf(e01, x0, acc1);
    }
    acc0 += acc0b; acc1 += acc1b;
    den0 += den0b; den1 += den1b;
    if (end > start) {
        acc0 /= den0;
        acc1 /= den1;
    }

    __syncthreads();                 // s_gw2 staged; also orders s_feat below
    s_feat[wv][lane] = acc0;         // idx = kb*16 + fb       = lane
    s_feat[wv][lane + 64] = acc1;    // idx = (kb+4)*16 + fb   = lane + 64
    __syncthreads();

    // h[b,n,lane] = sum_{f,k} feat[k*16+f*2+b] * GW[(f*8+k)*64+lane].
    // Per (k, fp): fe = {feat[k,2fp,b0], feat[k,2fp,b1], feat[k,2fp+1,b0],
    // feat[k,2fp+1,b1]} (float4 broadcast); g2 = {g[2fp*8+k][h], g[(2fp+1)*8+k][h]}.
    float h0 = 0.0f, h1 = 0.0f;
#pragma unroll
    for (int k = 0; k < 8; k++) {
#pragma unroll
        for (int fp = 0; fp < 4; fp++) {
            float4 fe = *(const float4*)&s_feat[wv][k * 16 + fp * 4];
            float2 g2 = *(const float2*)&s_gw2[((fp * 8 + k) * 64 + lane) * 2];
            h0 = fmaf(fe.x, g2.x, h0);
            h1 = fmaf(fe.y, g2.x, h1);
            h0 = fmaf(fe.z, g2.y, h0);
            h1 = fmaf(fe.w, g2.y, h1);
        }
    }
    if (valid) {
        out[(size_t)n * HC + lane] = h0;
        out[((size_t)N + n) * HC + lane] = h1;
    }
}

extern "C" void kernel_launch(void* const* d_in, const int* in_sizes, int n_in,
                              void* d_out, int out_size, void* d_ws, size_t ws_size,
                              hipStream_t stream) {
    const float* X      = (const float*)d_in[0];
    const float* u_val  = (const float*)d_in[1];
    const float* mu     = (const float*)d_in[2];
    const float* sigma  = (const float*)d_in[3];
    const float* GW     = (const float*)d_in[4];
    const int*   u_rows = (const int*)d_in[5];
    const int*   u_cols = (const int*)d_in[6];
    float* out = (float*)d_out;

    int E = in_sizes[5];
    int N = in_sizes[0] / (BC * FC);

    // Workspace (~29.5 MB): evals first for 32B alignment.
    float* evals   = (float*)d_ws;                       // E*8
    int* cols_s    = (int*)(evals + (size_t)E * KC);     // E
    int* counts    = cols_s + E;                         // N
    int* fill      = counts + N;                         // N
    int* row_start = fill + N;                           // N+1

    int nbE = (E + 255) / 256;
    int nbN = (N + 255) / 256;

    k0_zero<<<nbN, 256, 0, stream>>>(counts, N);
    k1_hist<<<nbE, 256, 0, stream>>>(u_rows, counts, E);
    k2_scan<<<1, 1024, 0, stream>>>(counts, row_start, fill, N, E);
    k3_evals<<<nbE, 256, 0, stream>>>(u_val, u_rows, u_cols, row_start, fill,
                                      mu, sigma, evals, cols_s, E);
    k4_row<<<(N + 3) / 4, 256, 0, stream>>>(X, evals, cols_s, row_start, GW, out, N);
}

// Round 7
// 236.516 us; speedup vs baseline: 1.4859x; 1.4859x over previous
//
#include <hip/hip_runtime.h>

// Problem constants (fixed by the reference):
//   B=2, N=50000, F=8, E=800000, D=3, K=8, H=64, FB=F*B=16, FK=F*K=64
#define KC 8
#define FC 8
#define BC 2
#define HC 64
#define KD 24        // K*D
#define EPSF 1e-14f

// ---------------- K0: zero degree counters + fill cursors ----------------
__global__ void k0_zero(int* __restrict__ counts, int* __restrict__ fill, int N) {
    int i = blockIdx.x * 256 + threadIdx.x;
    if (i < N) { counts[i] = 0; fill[i] = 0; }
}

// ---------------- K1: row-degree histogram ----------------
__global__ void k1_hist(const int* __restrict__ u_rows, int* __restrict__ counts, int E) {
    int e = blockIdx.x * 256 + threadIdx.x;
    if (e < E) atomicAdd(&counts[u_rows[e]], 1);
}

// ---------------- K2: hierarchical exclusive scan counts -> row_start ----------------
// R4 profile: single-block scan was 112us (4.5 GB/s, 0.14% occupancy — one CU,
// 196B-stride uncoalesced). Replaced by 3 small parallel coalesced kernels.
__global__ void k2a_scan_block(const int* __restrict__ counts, int* __restrict__ row_start,
                               int* __restrict__ bsum, int N) {
    __shared__ int s[256];
    int t = threadIdx.x;
    int i = blockIdx.x * 256 + t;
    int v = (i < N) ? counts[i] : 0;
    s[t] = v;
    __syncthreads();
    for (int off = 1; off < 256; off <<= 1) {
        int add = (t >= off) ? s[t - off] : 0;
        __syncthreads();
        s[t] += add;
        __syncthreads();
    }
    if (i < N) row_start[i] = s[t] - v;          // exclusive within block
    if (t == 255) bsum[blockIdx.x] = s[255];     // block total
}

__global__ void k2b_scan_bsums(int* __restrict__ bsum, int nb) {  // nb <= 256
    __shared__ int s[256];
    int t = threadIdx.x;
    int v = (t < nb) ? bsum[t] : 0;
    s[t] = v;
    __syncthreads();
    for (int off = 1; off < 256; off <<= 1) {
        int add = (t >= off) ? s[t - off] : 0;
        __syncthreads();
        s[t] += add;
        __syncthreads();
    }
    if (t < nb) bsum[t] = s[t] - v;              // exclusive block offsets
}

__global__ void k2c_add_offsets(int* __restrict__ row_start, const int* __restrict__ bsum,
                                int N, int E) {
    int i = blockIdx.x * 256 + threadIdx.x;
    if (i < N) row_start[i] += bsum[blockIdx.x];
    if (i == 0) row_start[N] = E;
}

// ---------------- K3: per-edge e-values (m=0 softmax numerator) into CSR slots ----------------
// Softmax is shift-invariant; logits <= 0 so e = exp(logit) in (0,1]. Full-row
// underflow would need every edge of a (row,k) below logit -87 (per-edge
// P ~ 2e-10 for this data) -> impossible; den > 0 always in practice.
// Each edge computed ONCE here (vs 16x redundantly per-lane in k4).
__global__ void k3_evals(const float* __restrict__ u_val, const int* __restrict__ u_rows,
                         const int* __restrict__ u_cols, const int* __restrict__ row_start,
                         int* __restrict__ fill, const float* __restrict__ mu,
                         const float* __restrict__ sigma, float* __restrict__ evals,
                         int* __restrict__ cols_s, int E) {
    __shared__ float s_mu[KD], s_inv[KD];
    int t = threadIdx.x;
    if (t < KD) { s_mu[t] = mu[t]; float sg = sigma[t]; s_inv[t] = 1.0f / (sg * sg + EPSF); }
    __syncthreads();
    int e = blockIdx.x * 256 + t;
    if (e >= E) return;
    int r = u_rows[e];
    int pos = row_start[r] + atomicAdd(&fill[r], 1);
    cols_s[pos] = u_cols[e];
    float v0 = u_val[e * 3 + 0], v1 = u_val[e * 3 + 1], v2 = u_val[e * 3 + 2];
    float ev[KC];
#pragma unroll
    for (int k = 0; k < KC; k++) {
        float d0 = v0 - s_mu[k * 3 + 0];
        float d1 = v1 - s_mu[k * 3 + 1];
        float d2 = v2 - s_mu[k * 3 + 2];
        float s = d0 * d0 * s_inv[k * 3 + 0];
        s = fmaf(d1 * d1, s_inv[k * 3 + 1], s);
        s = fmaf(d2 * d2, s_inv[k * 3 + 2], s);
        ev[k] = __expf(-0.5f * s);
    }
    float4* p = (float4*)(evals + (size_t)pos * KC);
    p[0] = make_float4(ev[0], ev[1], ev[2], ev[3]);
    p[1] = make_float4(ev[4], ev[5], ev[6], ev[7]);
}

// ---------------- K4: persistent-block row aggregation + fused 64x64 GEMM ----------------
// PERSISTENT blocks (R6): 2048 blocks grid-stride over 12500 row-groups; GW is
// staged into LDS ONCE per block (was: once per 4 rows = ~200MB aggregate L2
// traffic). s_feat is per-wave-private, so the group loop has NO barriers —
// same-wave LDS write->read is ordered by hardware lgkmcnt.
// One wave per row. lane = kb*16 + fb; fb = f*2 + b (matches X_t col f*B+b).
// Edge loop: evals read is SEQUENTIAL (CSR order, 32B/edge, coalesced); no LDS.
// Unnormalized accumulation + one divide at the end == per-edge normalization.
// GEMM: GW pair-interleaved [f/2][k][h][2] -> float2 reads (2-way alias = free),
// feats as float4 broadcasts.
__global__ __launch_bounds__(256) void k4_row(const float* __restrict__ X,
                                              const float* __restrict__ evals,
                                              const int* __restrict__ cols_s,
                                              const int* __restrict__ row_start,
                                              const float* __restrict__ GW,
                                              float* __restrict__ out, int N, int ngroups) {
    __shared__ float s_gw2[64 * 64];  // 16 KB: [fp=f>>1][k][h][f&1]
    __shared__ float s_feat[4][128];  // per-wave feats [k][fb] (wave-private)
    int t = threadIdx.x;
    // Stage GW swizzled: src i = fk*64 + h; dst = ((fp*8+k)*64 + h)*2 + (f&1).
    for (int i = t; i < 64 * 64; i += 256) {
        int fk = i >> 6, h = i & 63;
        int f = fk >> 3, k = fk & 7;
        int dst = (((f >> 1) * 8 + k) * 64 + h) * 2 + (f & 1);
        s_gw2[dst] = GW[i];
    }
    __syncthreads();                 // only barrier: s_gw2 visible to all waves

    int wv = t >> 6, lane = t & 63;
    int kb = lane >> 4, fb = lane & 15;
    int b = fb & 1, f = fb >> 1;
    const float* Xb = X + (size_t)b * (size_t)N * FC + f;   // X[b, c, f] at Xb[c*8]

    for (int g = blockIdx.x; g < ngroups; g += gridDim.x) {
        int n = g * 4 + wv;
        bool valid = (n < N);
        int start = valid ? row_start[n] : 0;
        int end   = valid ? row_start[n + 1] : 0;

        float acc0 = 0.0f, acc1 = 0.0f, den0 = 0.0f, den1 = 0.0f;
        float acc0b = 0.0f, acc1b = 0.0f, den0b = 0.0f, den1b = 0.0f;
        int i = start;
        for (; i + 1 < end; i += 2) {  // 2x unroll, independent accumulators for ILP
            float e00 = evals[(size_t)i * KC + kb];
            float e01 = evals[(size_t)i * KC + kb + 4];
            float e10 = evals[(size_t)(i + 1) * KC + kb];
            float e11 = evals[(size_t)(i + 1) * KC + kb + 4];
            int c0 = cols_s[i];
            int c1 = cols_s[i + 1];
            float x0 = Xb[(size_t)c0 * FC];
            float x1 = Xb[(size_t)c1 * FC];
            den0  += e00; den1  += e01;
            den0b += e10; den1b += e11;
            acc0  = fmaf(e00, x0, acc0);
            acc1  = fmaf(e01, x0, acc1);
            acc0b = fmaf(e10, x1, acc0b);
            acc1b = fmaf(e11, x1, acc1b);
        }
        if (i < end) {
            float e00 = evals[(size_t)i * KC + kb];
            float e01 = evals[(size_t)i * KC + kb + 4];
            int c0 = cols_s[i];
            float x0 = Xb[(size_t)c0 * FC];
            den0 += e00; den1 += e01;
            acc0 = fmaf(e00, x0, acc0);
            acc1 = fmaf(e01, x0, acc1);
        }
        acc0 += acc0b; acc1 += acc1b;
        den0 += den0b; den1 += den1b;
        if (end > start) {
            acc0 /= den0;
            acc1 /= den1;
        }

        s_feat[wv][lane] = acc0;         // idx = kb*16 + fb       = lane
        s_feat[wv][lane + 64] = acc1;    // idx = (kb+4)*16 + fb   = lane + 64
        // wave-private LDS: hardware lgkmcnt orders write->read, no barrier

        // h[b,n,lane] = sum_{f,k} feat[k*16+f*2+b] * GW[(f*8+k)*64+lane].
        float h0 = 0.0f, h1 = 0.0f;
#pragma unroll
        for (int k = 0; k < 8; k++) {
#pragma unroll
            for (int fp = 0; fp < 4; fp++) {
                float4 fe = *(const float4*)&s_feat[wv][k * 16 + fp * 4];
                float2 g2 = *(const float2*)&s_gw2[((fp * 8 + k) * 64 + lane) * 2];
                h0 = fmaf(fe.x, g2.x, h0);
                h1 = fmaf(fe.y, g2.x, h1);
                h0 = fmaf(fe.z, g2.y, h0);
                h1 = fmaf(fe.w, g2.y, h1);
            }
        }
        if (valid) {
            out[(size_t)n * HC + lane] = h0;
            out[((size_t)N + n) * HC + lane] = h1;
        }
    }
}

extern "C" void kernel_launch(void* const* d_in, const int* in_sizes, int n_in,
                              void* d_out, int out_size, void* d_ws, size_t ws_size,
                              hipStream_t stream) {
    const float* X      = (const float*)d_in[0];
    const float* u_val  = (const float*)d_in[1];
    const float* mu     = (const float*)d_in[2];
    const float* sigma  = (const float*)d_in[3];
    const float* GW     = (const float*)d_in[4];
    const int*   u_rows = (const int*)d_in[5];
    const int*   u_cols = (const int*)d_in[6];
    float* out = (float*)d_out;

    int E = in_sizes[5];
    int N = in_sizes[0] / (BC * FC);

    // Workspace (~29.7 MB, same layout as R4/R5): evals first for 32B alignment.
    float* evals   = (float*)d_ws;                       // E*8
    int* cols_s    = (int*)(evals + (size_t)E * KC);     // E
    int* counts    = cols_s + E;                         // N
    int* fill      = counts + N;                         // N
    int* row_start = fill + N;                           // N+1
    int* bsum      = row_start + (N + 1);                // 256

    int nbE = (E + 255) / 256;
    int nbN = (N + 255) / 256;   // 196 (must stay <= 256 for k2b)
    int ngroups = (N + 3) / 4;   // 12500
    int grid4 = 2048;            // persistent: 8 blocks/CU resident, grid-stride

    k0_zero<<<nbN, 256, 0, stream>>>(counts, fill, N);
    k1_hist<<<nbE, 256, 0, stream>>>(u_rows, counts, E);
    k2a_scan_block<<<nbN, 256, 0, stream>>>(counts, row_start, bsum, N);
    k2b_scan_bsums<<<1, 256, 0, stream>>>(bsum, nbN);
    k2c_add_offsets<<<nbN, 256, 0, stream>>>(row_start, bsum, N, E);
    k3_evals<<<nbE, 256, 0, stream>>>(u_val, u_rows, u_cols, row_start, fill,
                                      mu, sigma, evals, cols_s, E);
    k4_row<<<grid4, 256, 0, stream>>>(X, evals, cols_s, row_start, GW, out, N, ngroups);
}